// Round 1
// 485.245 us; speedup vs baseline: 1.0288x; 1.0288x over previous
//
#include <hip/hip_runtime.h>

#define Bb 1024
#define NN 50
#define KK 8
#define DD 128
#define CC 51

typedef __attribute__((ext_vector_type(8))) short short8;
typedef __attribute__((ext_vector_type(4))) float f32x4;

__device__ __forceinline__ unsigned short f2bf(float f) {
  union { float f; unsigned int u; } un; un.f = f;
  unsigned int r = un.u + 0x7fffu + ((un.u >> 16) & 1u);
  return (unsigned short)(r >> 16);
}
__device__ __forceinline__ float bf2f(unsigned short h) {
  union { unsigned int u; float f; } un; un.u = ((unsigned int)h) << 16;
  return un.f;
}

// ---------------- workspace layout ----------------
// H1bf (bf16, B*51*128) | bn accums (256 f32) | h2 (B*128 f32)
static constexpr size_t SZ_BCD   = (size_t)Bb * CC * DD;
static constexpr size_t BYTES_H1 = SZ_BCD * 2;        // 13369344, 256B-aligned
static constexpr size_t OFF_BN   = BYTES_H1;
static constexpr size_t OFF_H2   = OFF_BN + 1024;

// ---------------- kA: gather + attention + (Y@gcnW^T) + (adj@X) fused ----------------
// Per-b locality: Y and X live only in LDS. Only H1 + bn1 stats leave the block.
__global__ __launch_bounds__(256) void kA_fused(
    const int* __restrict__ hrt, const int* __restrict__ neb,
    const int* __restrict__ nebr, const float* __restrict__ entW,
    const float* __restrict__ relW, const float* __restrict__ attW,
    const float* __restrict__ attb, const float* __restrict__ gcnW,
    const float* __restrict__ gcnb, const float* __restrict__ adj,
    unsigned short* __restrict__ H1bf, float* __restrict__ bn1,
    float* __restrict__ out) {
  int b = blockIdx.x, t = threadIdx.x;   // 256 threads
  // sub row 0 = sum_hrt, rows 1..50 = subg, row 51 = zeros (MFMA pad)
  __shared__ float sub[52 * 132];                     // 27456 B
  __shared__ __align__(16) unsigned short Xbl[52 * 136]; // 14144 B (bf16 X, as before)
  __shared__ float Al[51 * 52];                       // 10608 B (adj, col 51 zero-pad)
  __shared__ float sq[DD], sw[DD];
  __shared__ float red[256];
  __shared__ float sl[NN];
  __shared__ float cval;

  // --- stage adj early (only needed in phase 3; overlaps the gathers) ---
  for (int idx = t; idx < 51 * 52; idx += 256) {
    int i = idx / 52, j = idx - i * 52;
    Al[idx] = (j < 51) ? adj[(size_t)b * (CC * CC) + i * CC + j] : 0.f;
  }
  // --- hrt gathers + sum_hrt -> sub row 0 ; zero pad row 51 ---
  if (t < 32) {
    int hi = hrt[b * 3 + 0], ri = hrt[b * 3 + 1], ti = hrt[b * 3 + 2];
    float4 hv = ((const float4*)(entW + (size_t)hi * DD))[t];
    float4 tv = ((const float4*)(entW + (size_t)ti * DD))[t];
    float4 rv = ((const float4*)(relW + (size_t)ri * DD))[t];
    ((float4*)(out + (size_t)b * DD))[t] = hv;
    ((float4*)(out + (size_t)Bb * DD + (size_t)b * DD))[t] = tv;
    ((float4*)(out + (size_t)2 * Bb * DD + (size_t)b * DD))[t] = rv;
    const float inv3 = 1.f / 3.f;
    float4 s;
    s.x = (hv.x + tv.x + rv.x) * inv3;
    s.y = (hv.y + tv.y + rv.y) * inv3;
    s.z = (hv.z + tv.z + rv.z) * inv3;
    s.w = (hv.w + tv.w + rv.w) * inv3;
    ((float4*)sub)[t] = s;
    ((float4*)(sub + 51 * 132))[t] = make_float4(0.f, 0.f, 0.f, 0.f);
  }
  // --- neighbor rows -> sub rows 1..50 ---
  for (int idx = t; idx < NN * 32; idx += 256) {
    int r = idx >> 5, c4 = idx & 31;
    int e = neb[b * NN + r];
    float4 ev = ((const float4*)(entW + (size_t)e * DD))[c4];
    const int* rb = nebr + ((size_t)(b * NN + r)) * KK;
    float4 rs = make_float4(0.f, 0.f, 0.f, 0.f);
#pragma unroll
    for (int k = 0; k < KK; ++k) {
      float4 rv = ((const float4*)(relW + (size_t)rb[k] * DD))[c4];
      rs.x += rv.x; rs.y += rv.y; rs.z += rv.z; rs.w += rv.w;
    }
    float4 sg;
    sg.x = 0.5f * (ev.x + rs.x * 0.125f);
    sg.y = 0.5f * (ev.y + rs.y * 0.125f);
    sg.z = 0.5f * (ev.z + rs.z * 0.125f);
    sg.w = 0.5f * (ev.w + rs.w * 0.125f);
    ((float4*)(sub + (r + 1) * 132))[c4] = sg;
  }
  __syncthreads();
  // --- q[d] = sum_e ss[e]*attW[d][e] + attb[d], lanes traverse e (coalesced) ---
  {
    int wv = t >> 6, l = t & 63, half = l >> 5, l32 = l & 31;
    float4 sv = ((const float4*)sub)[l32];   // row 0 = sum_hrt
#pragma unroll 4
    for (int j = 0; j < 16; ++j) {
      int d = 32 * wv + 2 * j + half;
      float4 wr = ((const float4*)(attW + (size_t)d * DD))[l32];
      float p = wr.x * sv.x + wr.y * sv.y + wr.z * sv.z + wr.w * sv.w;
#pragma unroll
      for (int m = 1; m < 32; m <<= 1) p += __shfl_xor(p, m);
      if (l32 == 0) sq[d] = p + attb[d];
    }
  }
  __syncthreads();
  // --- w[d] = sum_k sq[k]*attW[k][d] (coalesced over d); halves over k ---
  {
    int d = t & 127, k0 = (t >> 7) * 64;
    float wp = 0.f;
#pragma unroll 4
    for (int k = 0; k < 64; ++k)
      wp += sq[k0 + k] * attW[(size_t)(k0 + k) * DD + d];
    red[t] = wp;
  }
  __syncthreads();
  if (t < 128) sw[t] = red[t] + red[t + 128];
  if (t < 64) {   // cval = q . attb
    float v = sq[t] * attb[t] + sq[t + 64] * attb[t + 64];
#pragma unroll
    for (int m = 1; m < 64; m <<= 1) v += __shfl_xor(v, m);
    if (t == 0) cval = v;
  }
  __syncthreads();
  // --- logits: 4 threads per row n ---
  if (t < NN * 4) {
    int n = t >> 2, q = t & 3;
    const float* sg = sub + (n + 1) * 132 + q * 32;
    const float* wq = sw + q * 32;
    float L = 0.f;
#pragma unroll 8
    for (int e = 0; e < 32; ++e) L += sg[e] * wq[e];
    L += __shfl_xor(L, 1);
    L += __shfl_xor(L, 2);
    if (q == 0) {
      L += cval;
      sl[n] = (L > 0.f) ? L : 0.01f * L;
    }
  }
  __syncthreads();
  // --- softmax over 50 (wave 0) ---
  if (t < 64) {
    float v = (t < NN) ? sl[t] : -1e30f;
    float mx = v;
#pragma unroll
    for (int m = 1; m < 64; m <<= 1) mx = fmaxf(mx, __shfl_xor(mx, m));
    float e = (t < NN) ? __expf(v - mx) : 0.f;
    float sm = e;
#pragma unroll
    for (int m = 1; m < 64; m <<= 1) sm += __shfl_xor(sm, m);
    if (t < NN) sl[t] = e / sm;
  }
  __syncthreads();
  // --- phase 2: X = Y @ gcnW^T + b via MFMA. Y = scale(row)*sub(row), built
  //     on the fly in the A-fragment load (Y is never materialized).
  //     4 waves as 2M x 2N; B-fragments read f32 gcnW from L2 + cvt in reg. ---
  {
    int wv = t >> 6, lane = t & 63;
    int wm = wv >> 1, wn = wv & 1;
    int m16 = lane & 15, g = lane >> 4, q8 = g * 8;
    f32x4 acc[2][4] = {};
    int rowA[2]; float sc[2];
#pragma unroll
    for (int mt = 0; mt < 2; ++mt) {
      int row = wm * 32 + mt * 16 + m16;
      rowA[mt] = (row <= 51) ? row : 51;            // row 51 = zeros
      sc[mt] = (row == 0) ? 1.f : ((row <= 50) ? sl[row - 1] : 0.f);
    }
#pragma unroll
    for (int ks = 0; ks < 4; ++ks) {
      short8 afr[2];
#pragma unroll
      for (int mt = 0; mt < 2; ++mt) {
        const float* ap = sub + rowA[mt] * 132 + ks * 32 + q8;
        float4 v0 = ((const float4*)ap)[0];
        float4 v1 = ((const float4*)ap)[1];
        short8 a;
        a[0] = (short)f2bf(sc[mt] * v0.x); a[1] = (short)f2bf(sc[mt] * v0.y);
        a[2] = (short)f2bf(sc[mt] * v0.z); a[3] = (short)f2bf(sc[mt] * v0.w);
        a[4] = (short)f2bf(sc[mt] * v1.x); a[5] = (short)f2bf(sc[mt] * v1.y);
        a[6] = (short)f2bf(sc[mt] * v1.z); a[7] = (short)f2bf(sc[mt] * v1.w);
        afr[mt] = a;
      }
#pragma unroll
      for (int nt = 0; nt < 4; ++nt) {
        int n = wn * 64 + nt * 16 + m16;
        const float* bp = gcnW + (size_t)n * DD + ks * 32 + q8;
        float4 b0 = ((const float4*)bp)[0];
        float4 b1 = ((const float4*)bp)[1];
        short8 bf;
        bf[0] = (short)f2bf(b0.x); bf[1] = (short)f2bf(b0.y);
        bf[2] = (short)f2bf(b0.z); bf[3] = (short)f2bf(b0.w);
        bf[4] = (short)f2bf(b1.x); bf[5] = (short)f2bf(b1.y);
        bf[6] = (short)f2bf(b1.z); bf[7] = (short)f2bf(b1.w);
        acc[0][nt] = __builtin_amdgcn_mfma_f32_16x16x32_bf16(afr[0], bf, acc[0][nt], 0, 0, 0);
        acc[1][nt] = __builtin_amdgcn_mfma_f32_16x16x32_bf16(afr[1], bf, acc[1][nt], 0, 0, 0);
      }
    }
    // epilogue -> Xbl (bf16, same rounding as the old Xbf path)
    int qd = g * 4;
#pragma unroll
    for (int mt = 0; mt < 2; ++mt) {
#pragma unroll
      for (int nt = 0; nt < 4; ++nt) {
        int col = wn * 64 + nt * 16 + m16;
        float bias = gcnb[col];
#pragma unroll
        for (int r = 0; r < 4; ++r) {
          int row = wm * 32 + mt * 16 + qd + r;
          if (row < 52) Xbl[row * 136 + col] = f2bf(acc[mt][nt][r] + bias);
        }
      }
    }
  }
  __syncthreads();
  // --- phase 3: H1 = relu(adj_b @ X), BN1 partial stats (from LDS only) ---
  {
    int tc = t & 15, tr = t >> 4;   // tr 0..15, each owns rows tr+16k
    float4 acc0[4], acc1[4];
#pragma unroll
    for (int k = 0; k < 4; ++k) {
      acc0[k] = make_float4(0.f, 0.f, 0.f, 0.f);
      acc1[k] = make_float4(0.f, 0.f, 0.f, 0.f);
    }
    for (int jj4 = 0; jj4 < 13; ++jj4) {
      float4 av[4];
#pragma unroll
      for (int k = 0; k < 4; ++k) {
        int i = tr + 16 * k;
        av[k] = (i < 51) ? ((const float4*)(Al + i * 52))[jj4]
                         : make_float4(0.f, 0.f, 0.f, 0.f);
      }
#pragma unroll
      for (int ee = 0; ee < 4; ++ee) {
        int jj = jj4 * 4 + ee;
        uint4 v = ((const uint4*)(Xbl + jj * 136))[tc];   // cols 8tc..8tc+7
        float f0 = bf2f((unsigned short)(v.x & 0xffff));
        float f1 = bf2f((unsigned short)(v.x >> 16));
        float f2 = bf2f((unsigned short)(v.y & 0xffff));
        float f3 = bf2f((unsigned short)(v.y >> 16));
        float f4 = bf2f((unsigned short)(v.z & 0xffff));
        float f5 = bf2f((unsigned short)(v.z >> 16));
        float f6 = bf2f((unsigned short)(v.w & 0xffff));
        float f7 = bf2f((unsigned short)(v.w >> 16));
#pragma unroll
        for (int k = 0; k < 4; ++k) {
          float a = (ee == 0) ? av[k].x : (ee == 1) ? av[k].y
                    : (ee == 2) ? av[k].z : av[k].w;
          acc0[k].x += a * f0; acc0[k].y += a * f1;
          acc0[k].z += a * f2; acc0[k].w += a * f3;
          acc1[k].x += a * f4; acc1[k].y += a * f5;
          acc1[k].z += a * f6; acc1[k].w += a * f7;
        }
      }
    }
#pragma unroll
    for (int k = 0; k < 4; ++k) {
      int i = tr + 16 * k;
      if (i < 51) {
        float4 h0, h1v;
        h0.x = fmaxf(acc0[k].x, 0.f); h0.y = fmaxf(acc0[k].y, 0.f);
        h0.z = fmaxf(acc0[k].z, 0.f); h0.w = fmaxf(acc0[k].w, 0.f);
        h1v.x = fmaxf(acc1[k].x, 0.f); h1v.y = fmaxf(acc1[k].y, 0.f);
        h1v.z = fmaxf(acc1[k].z, 0.f); h1v.w = fmaxf(acc1[k].w, 0.f);
        size_t rowoff = ((size_t)b * CC + i) * DD;
        ushort4 p0, p1;
        p0.x = f2bf(h0.x); p0.y = f2bf(h0.y); p0.z = f2bf(h0.z); p0.w = f2bf(h0.w);
        p1.x = f2bf(h1v.x); p1.y = f2bf(h1v.y); p1.z = f2bf(h1v.z); p1.w = f2bf(h1v.w);
        ((ushort4*)(H1bf + rowoff))[2 * tc]     = p0;
        ((ushort4*)(H1bf + rowoff))[2 * tc + 1] = p1;
        float s = h0.x + h0.y + h0.z + h0.w + h1v.x + h1v.y + h1v.z + h1v.w;
        float qq = h0.x * h0.x + h0.y * h0.y + h0.z * h0.z + h0.w * h0.w +
                   h1v.x * h1v.x + h1v.y * h1v.y + h1v.z * h1v.z + h1v.w * h1v.w;
#pragma unroll
        for (int m = 1; m < 16; m <<= 1) {
          s += __shfl_xor(s, m);
          qq += __shfl_xor(qq, m);
        }
        if (tc == 0) {
          atomicAdd(&bn1[i], s);
          atomicAdd(&bn1[64 + i], qq);
        }
      }
    }
  }
}

// ---------------- K6: h2 = relu(adj0 @ BN1(H1)), BN2 partial stats ----------------
__global__ __launch_bounds__(128) void k6_row0(
    const unsigned short* __restrict__ H1bf, const float* __restrict__ adj,
    const float* __restrict__ bn1, const float* __restrict__ gamma,
    const float* __restrict__ beta, float* __restrict__ h2,
    float* __restrict__ bn2) {
  __shared__ float cj[52];
  __shared__ float td[64];
  __shared__ float reds[128], redq[128];
  int b = blockIdx.x, t = threadIdx.x;   // t == d
  const float invBD = 1.f / ((float)Bb * (float)DD);
  if (t < 64) td[t] = 0.f;
  if (t < 51) {
    float s = bn1[t], q = bn1[64 + t];
    float m = s * invBD;
    float v = fmaxf(q * invBD - m * m, 0.f);
    float inv = rsqrtf(v + 1e-5f);
    float al = gamma[t] * inv;
    float de = beta[t] - m * al;
    float a0 = adj[(size_t)b * (CC * CC) + t];
    cj[t] = a0 * al;
    td[t] = a0 * de;
  }
  __syncthreads();
  float tcst = 0.f;
  for (int j = 0; j < 51; ++j) tcst += td[j];
  float acc = tcst;
  const unsigned short* hb = H1bf + (size_t)b * CC * DD + t;
#pragma unroll 4
  for (int j = 0; j < 51; ++j) acc += cj[j] * bf2f(hb[(size_t)j * DD]);
  acc = fmaxf(acc, 0.f);
  h2[(size_t)b * DD + t] = acc;
  reds[t] = acc;
  redq[t] = acc * acc;
  __syncthreads();
  for (int s = 64; s > 0; s >>= 1) {
    if (t < s) { reds[t] += reds[t + s]; redq[t] += redq[t + s]; }
    __syncthreads();
  }
  if (t == 0) {
    atomicAdd(&bn2[0], reds[0]);
    atomicAdd(&bn2[1], redq[0]);
  }
}

// ---------------- K8: tri_em = BN2(h2) ----------------
__global__ __launch_bounds__(256) void k8_final(
    const float* __restrict__ h2, const float* __restrict__ bn2,
    const float* __restrict__ gamma, const float* __restrict__ beta,
    float* __restrict__ out) {
  int i = blockIdx.x * 256 + threadIdx.x;
  const float invBD = 1.f / ((float)Bb * (float)DD);
  float m = bn2[0] * invBD;
  float v = fmaxf(bn2[1] * invBD - m * m, 0.f);
  float inv = rsqrtf(v + 1e-5f);
  out[(size_t)3 * Bb * DD + i] = (h2[i] - m) * inv * gamma[0] + beta[0];
}

extern "C" void kernel_launch(void* const* d_in, const int* in_sizes, int n_in,
                              void* d_out, int out_size, void* d_ws, size_t ws_size,
                              hipStream_t stream) {
  (void)in_sizes; (void)n_in; (void)out_size; (void)ws_size;
  const int*   hrt   = (const int*)d_in[0];
  const int*   neb   = (const int*)d_in[1];
  const int*   nebr  = (const int*)d_in[2];
  const float* adj   = (const float*)d_in[3];
  const float* entW  = (const float*)d_in[4];
  const float* relW  = (const float*)d_in[5];
  const float* attW  = (const float*)d_in[6];
  const float* attb  = (const float*)d_in[7];
  const float* gcnW  = (const float*)d_in[8];
  const float* gcnb  = (const float*)d_in[9];
  const float* gamma = (const float*)d_in[10];
  const float* beta  = (const float*)d_in[11];
  float* out = (float*)d_out;
  char*  ws  = (char*)d_ws;

  unsigned short* H1bf = (unsigned short*)ws;
  float*          bn1  = (float*)(ws + OFF_BN);
  float*          bn2  = bn1 + 128;
  float*          h2   = (float*)(ws + OFF_H2);

  hipMemsetAsync((void*)bn1, 0, 1024, stream);   // zero BN accumulators

  kA_fused<<<Bb, 256, 0, stream>>>(hrt, neb, nebr, entW, relW, attW, attb,
                                   gcnW, gcnb, adj, H1bf, bn1, out);
  k6_row0<<<Bb, 128, 0, stream>>>(H1bf, adj, bn1, gamma, beta, h2, bn2);
  k8_final<<<(Bb * DD) / 256, 256, 0, stream>>>(h2, bn2, gamma, beta, out);
}

// Round 2
// 481.350 us; speedup vs baseline: 1.0372x; 1.0081x over previous
//
#include <hip/hip_runtime.h>

#define Bb 1024
#define NN 50
#define KK 8
#define DD 128
#define CC 51

typedef __attribute__((ext_vector_type(8))) short short8;
typedef __attribute__((ext_vector_type(4))) float f32x4;

__device__ __forceinline__ unsigned short f2bf(float f) {
  union { float f; unsigned int u; } un; un.f = f;
  unsigned int r = un.u + 0x7fffu + ((un.u >> 16) & 1u);
  return (unsigned short)(r >> 16);
}
__device__ __forceinline__ float bf2f(unsigned short h) {
  union { unsigned int u; float f; } un; un.u = ((unsigned int)h) << 16;
  return un.f;
}

// ---------------- workspace layout ----------------
// H1bf (bf16, B*51*128) | bn accums (256 f32) | h2 (B*128 f32)
static constexpr size_t SZ_BCD   = (size_t)Bb * CC * DD;
static constexpr size_t BYTES_H1 = SZ_BCD * 2;        // 13369344, 256B-aligned
static constexpr size_t OFF_BN   = BYTES_H1;
static constexpr size_t OFF_H2   = OFF_BN + 1024;

// ---------------- kA: gather + attention + (Y@gcnW^T) + (adj@X) fused ----------------
// LDS budget 39.3 KB -> 4 blocks/CU (16 waves/CU): all 1024 blocks co-resident.
// Xbl (bf16 X) is UNIONED into sub's storage (sub is dead after the MFMA reads).
__global__ __launch_bounds__(256, 4) void kA_fused(
    const int* __restrict__ hrt, const int* __restrict__ neb,
    const int* __restrict__ nebr, const float* __restrict__ entW,
    const float* __restrict__ relW, const float* __restrict__ attW,
    const float* __restrict__ attb, const float* __restrict__ gcnW,
    const float* __restrict__ gcnb, const float* __restrict__ adj,
    unsigned short* __restrict__ H1bf, float* __restrict__ bn1,
    float* __restrict__ out) {
  int b = blockIdx.x, t = threadIdx.x;   // 256 threads
  // sub row 0 = sum_hrt, rows 1..50 = subg, row 51 = zeros (MFMA pad)
  // later reused as Xbl: 52 x 136 ushort (14144 B <= 27456 B)
  __shared__ __align__(16) float sub[52 * 132];       // 27456 B
  __shared__ float Al[51 * 52];                       // 10608 B (adj, col 51 zero-pad)
  __shared__ float sq[DD], sw[DD];                    // 1024 B
  __shared__ float sl[NN];                            // 200 B
  __shared__ float cval;
  unsigned short* Xbl = (unsigned short*)sub;         // union (after barrier)

  // --- stage adj early (only needed in phase 3; overlaps the gathers) ---
  for (int idx = t; idx < 51 * 52; idx += 256) {
    int i = idx / 52, j = idx - i * 52;
    Al[idx] = (j < 51) ? adj[(size_t)b * (CC * CC) + i * CC + j] : 0.f;
  }
  // --- hrt gathers + sum_hrt -> sub row 0 ; zero pad row 51 ---
  if (t < 32) {
    int hi = hrt[b * 3 + 0], ri = hrt[b * 3 + 1], ti = hrt[b * 3 + 2];
    float4 hv = ((const float4*)(entW + (size_t)hi * DD))[t];
    float4 tv = ((const float4*)(entW + (size_t)ti * DD))[t];
    float4 rv = ((const float4*)(relW + (size_t)ri * DD))[t];
    ((float4*)(out + (size_t)b * DD))[t] = hv;
    ((float4*)(out + (size_t)Bb * DD + (size_t)b * DD))[t] = tv;
    ((float4*)(out + (size_t)2 * Bb * DD + (size_t)b * DD))[t] = rv;
    const float inv3 = 1.f / 3.f;
    float4 s;
    s.x = (hv.x + tv.x + rv.x) * inv3;
    s.y = (hv.y + tv.y + rv.y) * inv3;
    s.z = (hv.z + tv.z + rv.z) * inv3;
    s.w = (hv.w + tv.w + rv.w) * inv3;
    ((float4*)sub)[t] = s;
    ((float4*)(sub + 51 * 132))[t] = make_float4(0.f, 0.f, 0.f, 0.f);
  }
  // --- neighbor rows -> sub rows 1..50 ---
  for (int idx = t; idx < NN * 32; idx += 256) {
    int r = idx >> 5, c4 = idx & 31;
    int e = neb[b * NN + r];
    float4 ev = ((const float4*)(entW + (size_t)e * DD))[c4];
    const int* rb = nebr + ((size_t)(b * NN + r)) * KK;
    float4 rs = make_float4(0.f, 0.f, 0.f, 0.f);
#pragma unroll
    for (int k = 0; k < KK; ++k) {
      float4 rv = ((const float4*)(relW + (size_t)rb[k] * DD))[c4];
      rs.x += rv.x; rs.y += rv.y; rs.z += rv.z; rs.w += rv.w;
    }
    float4 sg;
    sg.x = 0.5f * (ev.x + rs.x * 0.125f);
    sg.y = 0.5f * (ev.y + rs.y * 0.125f);
    sg.z = 0.5f * (ev.z + rs.z * 0.125f);
    sg.w = 0.5f * (ev.w + rs.w * 0.125f);
    ((float4*)(sub + (r + 1) * 132))[c4] = sg;
  }
  __syncthreads();
  // --- q[d] = sum_e ss[e]*attW[d][e] + attb[d], lanes traverse e (coalesced) ---
  {
    int wv = t >> 6, l = t & 63, half = l >> 5, l32 = l & 31;
    float4 sv = ((const float4*)sub)[l32];   // row 0 = sum_hrt
#pragma unroll 4
    for (int j = 0; j < 16; ++j) {
      int d = 32 * wv + 2 * j + half;
      float4 wr = ((const float4*)(attW + (size_t)d * DD))[l32];
      float p = wr.x * sv.x + wr.y * sv.y + wr.z * sv.z + wr.w * sv.w;
#pragma unroll
      for (int m = 1; m < 32; m <<= 1) p += __shfl_xor(p, m);
      if (l32 == 0) sq[d] = p + attb[d];
    }
  }
  __syncthreads();
  // --- w[d] = sum_k sq[k]*attW[k][d] on threads 0..127 (full-k, 4 split accs);
  //     cval = q . attb on wave 2 concurrently. No LDS scratch needed. ---
  if (t < 128) {
    float w0 = 0.f, w1 = 0.f, w2 = 0.f, w3 = 0.f;
    const float* wc = attW + t;
#pragma unroll 8
    for (int k = 0; k < 128; k += 4) {
      w0 += sq[k]     * wc[(size_t)k * DD];
      w1 += sq[k + 1] * wc[(size_t)(k + 1) * DD];
      w2 += sq[k + 2] * wc[(size_t)(k + 2) * DD];
      w3 += sq[k + 3] * wc[(size_t)(k + 3) * DD];
    }
    sw[t] = (w0 + w1) + (w2 + w3);
  } else if (t < 192) {
    int l = t - 128;
    float v = sq[l] * attb[l] + sq[l + 64] * attb[l + 64];
#pragma unroll
    for (int m = 1; m < 64; m <<= 1) v += __shfl_xor(v, m);
    if (l == 0) cval = v;
  }
  __syncthreads();
  // --- logits: 4 threads per row n ---
  if (t < NN * 4) {
    int n = t >> 2, q = t & 3;
    const float* sg = sub + (n + 1) * 132 + q * 32;
    const float* wq = sw + q * 32;
    float L = 0.f;
#pragma unroll 8
    for (int e = 0; e < 32; ++e) L += sg[e] * wq[e];
    L += __shfl_xor(L, 1);
    L += __shfl_xor(L, 2);
    if (q == 0) {
      L += cval;
      sl[n] = (L > 0.f) ? L : 0.01f * L;
    }
  }
  __syncthreads();
  // --- softmax over 50 (wave 0) ---
  if (t < 64) {
    float v = (t < NN) ? sl[t] : -1e30f;
    float mx = v;
#pragma unroll
    for (int m = 1; m < 64; m <<= 1) mx = fmaxf(mx, __shfl_xor(mx, m));
    float e = (t < NN) ? __expf(v - mx) : 0.f;
    float sm = e;
#pragma unroll
    for (int m = 1; m < 64; m <<= 1) sm += __shfl_xor(sm, m);
    if (t < NN) sl[t] = e / sm;
  }
  __syncthreads();
  // --- phase 2: X = Y @ gcnW^T + b via MFMA. Y = scale(row)*sub(row), built
  //     on the fly in the A-fragment load (Y is never materialized). ---
  {
    int wv = t >> 6, lane = t & 63;
    int wm = wv >> 1, wn = wv & 1;
    int m16 = lane & 15, g = lane >> 4, q8 = g * 8;
    f32x4 acc[2][4] = {};
    int rowA[2]; float sc[2];
#pragma unroll
    for (int mt = 0; mt < 2; ++mt) {
      int row = wm * 32 + mt * 16 + m16;
      rowA[mt] = (row <= 51) ? row : 51;            // row 51 = zeros
      sc[mt] = (row == 0) ? 1.f : ((row <= 50) ? sl[row - 1] : 0.f);
    }
#pragma unroll
    for (int ks = 0; ks < 4; ++ks) {
      short8 afr[2];
#pragma unroll
      for (int mt = 0; mt < 2; ++mt) {
        const float* ap = sub + rowA[mt] * 132 + ks * 32 + q8;
        float4 v0 = ((const float4*)ap)[0];
        float4 v1 = ((const float4*)ap)[1];
        short8 a;
        a[0] = (short)f2bf(sc[mt] * v0.x); a[1] = (short)f2bf(sc[mt] * v0.y);
        a[2] = (short)f2bf(sc[mt] * v0.z); a[3] = (short)f2bf(sc[mt] * v0.w);
        a[4] = (short)f2bf(sc[mt] * v1.x); a[5] = (short)f2bf(sc[mt] * v1.y);
        a[6] = (short)f2bf(sc[mt] * v1.z); a[7] = (short)f2bf(sc[mt] * v1.w);
        afr[mt] = a;
      }
#pragma unroll
      for (int nt = 0; nt < 4; ++nt) {
        int n = wn * 64 + nt * 16 + m16;
        const float* bp = gcnW + (size_t)n * DD + ks * 32 + q8;
        float4 b0 = ((const float4*)bp)[0];
        float4 b1 = ((const float4*)bp)[1];
        short8 bf;
        bf[0] = (short)f2bf(b0.x); bf[1] = (short)f2bf(b0.y);
        bf[2] = (short)f2bf(b0.z); bf[3] = (short)f2bf(b0.w);
        bf[4] = (short)f2bf(b1.x); bf[5] = (short)f2bf(b1.y);
        bf[6] = (short)f2bf(b1.z); bf[7] = (short)f2bf(b1.w);
        acc[0][nt] = __builtin_amdgcn_mfma_f32_16x16x32_bf16(afr[0], bf, acc[0][nt], 0, 0, 0);
        acc[1][nt] = __builtin_amdgcn_mfma_f32_16x16x32_bf16(afr[1], bf, acc[1][nt], 0, 0, 0);
      }
    }
    __syncthreads();   // all A-fragment reads of sub done -> safe to overwrite as Xbl
    // epilogue -> Xbl (bf16, aliases sub storage)
    int qd = g * 4;
#pragma unroll
    for (int mt = 0; mt < 2; ++mt) {
#pragma unroll
      for (int nt = 0; nt < 4; ++nt) {
        int col = wn * 64 + nt * 16 + m16;
        float bias = gcnb[col];
#pragma unroll
        for (int r = 0; r < 4; ++r) {
          int row = wm * 32 + mt * 16 + qd + r;
          if (row < 52) Xbl[row * 136 + col] = f2bf(acc[mt][nt][r] + bias);
        }
      }
    }
  }
  __syncthreads();
  // --- phase 3: H1 = relu(adj_b @ X), BN1 partial stats (from LDS only) ---
  {
    int tc = t & 15, tr = t >> 4;   // tr 0..15, each owns rows tr+16k
    float4 acc0[4], acc1[4];
#pragma unroll
    for (int k = 0; k < 4; ++k) {
      acc0[k] = make_float4(0.f, 0.f, 0.f, 0.f);
      acc1[k] = make_float4(0.f, 0.f, 0.f, 0.f);
    }
    for (int jj4 = 0; jj4 < 13; ++jj4) {
      float4 av[4];
#pragma unroll
      for (int k = 0; k < 4; ++k) {
        int i = tr + 16 * k;
        av[k] = (i < 51) ? ((const float4*)(Al + i * 52))[jj4]
                         : make_float4(0.f, 0.f, 0.f, 0.f);
      }
#pragma unroll
      for (int ee = 0; ee < 4; ++ee) {
        int jj = jj4 * 4 + ee;
        uint4 v = ((const uint4*)(Xbl + jj * 136))[tc];   // cols 8tc..8tc+7
        float f0 = bf2f((unsigned short)(v.x & 0xffff));
        float f1 = bf2f((unsigned short)(v.x >> 16));
        float f2 = bf2f((unsigned short)(v.y & 0xffff));
        float f3 = bf2f((unsigned short)(v.y >> 16));
        float f4 = bf2f((unsigned short)(v.z & 0xffff));
        float f5 = bf2f((unsigned short)(v.z >> 16));
        float f6 = bf2f((unsigned short)(v.w & 0xffff));
        float f7 = bf2f((unsigned short)(v.w >> 16));
#pragma unroll
        for (int k = 0; k < 4; ++k) {
          float a = (ee == 0) ? av[k].x : (ee == 1) ? av[k].y
                    : (ee == 2) ? av[k].z : av[k].w;
          acc0[k].x += a * f0; acc0[k].y += a * f1;
          acc0[k].z += a * f2; acc0[k].w += a * f3;
          acc1[k].x += a * f4; acc1[k].y += a * f5;
          acc1[k].z += a * f6; acc1[k].w += a * f7;
        }
      }
    }
#pragma unroll
    for (int k = 0; k < 4; ++k) {
      int i = tr + 16 * k;
      if (i < 51) {
        float4 h0, h1v;
        h0.x = fmaxf(acc0[k].x, 0.f); h0.y = fmaxf(acc0[k].y, 0.f);
        h0.z = fmaxf(acc0[k].z, 0.f); h0.w = fmaxf(acc0[k].w, 0.f);
        h1v.x = fmaxf(acc1[k].x, 0.f); h1v.y = fmaxf(acc1[k].y, 0.f);
        h1v.z = fmaxf(acc1[k].z, 0.f); h1v.w = fmaxf(acc1[k].w, 0.f);
        size_t rowoff = ((size_t)b * CC + i) * DD;
        ushort4 p0, p1;
        p0.x = f2bf(h0.x); p0.y = f2bf(h0.y); p0.z = f2bf(h0.z); p0.w = f2bf(h0.w);
        p1.x = f2bf(h1v.x); p1.y = f2bf(h1v.y); p1.z = f2bf(h1v.z); p1.w = f2bf(h1v.w);
        ((ushort4*)(H1bf + rowoff))[2 * tc]     = p0;
        ((ushort4*)(H1bf + rowoff))[2 * tc + 1] = p1;
        float s = h0.x + h0.y + h0.z + h0.w + h1v.x + h1v.y + h1v.z + h1v.w;
        float qq = h0.x * h0.x + h0.y * h0.y + h0.z * h0.z + h0.w * h0.w +
                   h1v.x * h1v.x + h1v.y * h1v.y + h1v.z * h1v.z + h1v.w * h1v.w;
#pragma unroll
        for (int m = 1; m < 16; m <<= 1) {
          s += __shfl_xor(s, m);
          qq += __shfl_xor(qq, m);
        }
        if (tc == 0) {
          atomicAdd(&bn1[i], s);
          atomicAdd(&bn1[64 + i], qq);
        }
      }
    }
  }
}

// ---------------- K6: h2 = relu(adj0 @ BN1(H1)), BN2 partial stats ----------------
__global__ __launch_bounds__(128) void k6_row0(
    const unsigned short* __restrict__ H1bf, const float* __restrict__ adj,
    const float* __restrict__ bn1, const float* __restrict__ gamma,
    const float* __restrict__ beta, float* __restrict__ h2,
    float* __restrict__ bn2) {
  __shared__ float cj[52];
  __shared__ float td[64];
  __shared__ float reds[128], redq[128];
  int b = blockIdx.x, t = threadIdx.x;   // t == d
  const float invBD = 1.f / ((float)Bb * (float)DD);
  if (t < 64) td[t] = 0.f;
  if (t < 51) {
    float s = bn1[t], q = bn1[64 + t];
    float m = s * invBD;
    float v = fmaxf(q * invBD - m * m, 0.f);
    float inv = rsqrtf(v + 1e-5f);
    float al = gamma[t] * inv;
    float de = beta[t] - m * al;
    float a0 = adj[(size_t)b * (CC * CC) + t];
    cj[t] = a0 * al;
    td[t] = a0 * de;
  }
  __syncthreads();
  float tcst = 0.f;
  for (int j = 0; j < 51; ++j) tcst += td[j];
  float acc = tcst;
  const unsigned short* hb = H1bf + (size_t)b * CC * DD + t;
#pragma unroll 4
  for (int j = 0; j < 51; ++j) acc += cj[j] * bf2f(hb[(size_t)j * DD]);
  acc = fmaxf(acc, 0.f);
  h2[(size_t)b * DD + t] = acc;
  reds[t] = acc;
  redq[t] = acc * acc;
  __syncthreads();
  for (int s = 64; s > 0; s >>= 1) {
    if (t < s) { reds[t] += reds[t + s]; redq[t] += redq[t + s]; }
    __syncthreads();
  }
  if (t == 0) {
    atomicAdd(&bn2[0], reds[0]);
    atomicAdd(&bn2[1], redq[0]);
  }
}

// ---------------- K8: tri_em = BN2(h2) ----------------
__global__ __launch_bounds__(256) void k8_final(
    const float* __restrict__ h2, const float* __restrict__ bn2,
    const float* __restrict__ gamma, const float* __restrict__ beta,
    float* __restrict__ out) {
  int i = blockIdx.x * 256 + threadIdx.x;
  const float invBD = 1.f / ((float)Bb * (float)DD);
  float m = bn2[0] * invBD;
  float v = fmaxf(bn2[1] * invBD - m * m, 0.f);
  float inv = rsqrtf(v + 1e-5f);
  out[(size_t)3 * Bb * DD + i] = (h2[i] - m) * inv * gamma[0] + beta[0];
}

extern "C" void kernel_launch(void* const* d_in, const int* in_sizes, int n_in,
                              void* d_out, int out_size, void* d_ws, size_t ws_size,
                              hipStream_t stream) {
  (void)in_sizes; (void)n_in; (void)out_size; (void)ws_size;
  const int*   hrt   = (const int*)d_in[0];
  const int*   neb   = (const int*)d_in[1];
  const int*   nebr  = (const int*)d_in[2];
  const float* adj   = (const float*)d_in[3];
  const float* entW  = (const float*)d_in[4];
  const float* relW  = (const float*)d_in[5];
  const float* attW  = (const float*)d_in[6];
  const float* attb  = (const float*)d_in[7];
  const float* gcnW  = (const float*)d_in[8];
  const float* gcnb  = (const float*)d_in[9];
  const float* gamma = (const float*)d_in[10];
  const float* beta  = (const float*)d_in[11];
  float* out = (float*)d_out;
  char*  ws  = (char*)d_ws;

  unsigned short* H1bf = (unsigned short*)ws;
  float*          bn1  = (float*)(ws + OFF_BN);
  float*          bn2  = bn1 + 128;
  float*          h2   = (float*)(ws + OFF_H2);

  hipMemsetAsync((void*)bn1, 0, 1024, stream);   // zero BN accumulators

  kA_fused<<<Bb, 256, 0, stream>>>(hrt, neb, nebr, entW, relW, attW, attb,
                                   gcnW, gcnb, adj, H1bf, bn1, out);
  k6_row0<<<Bb, 128, 0, stream>>>(H1bf, adj, bn1, gamma, beta, h2, bn2);
  k8_final<<<(Bb * DD) / 256, 256, 0, stream>>>(h2, bn2, gamma, beta, out);
}